// Round 6
// baseline (406.281 us; speedup 1.0000x reference)
//
#include <hip/hip_runtime.h>

#define TT   256
#define HID  30
#define LOG2E 1.4426950408889634f

typedef __bf16 bf16x8_t __attribute__((ext_vector_type(8)));
typedef float  f32x4_t  __attribute__((ext_vector_type(4)));
typedef unsigned int u32x4_t __attribute__((ext_vector_type(4)));

__device__ __forceinline__ float fexp2(float x){
#if __has_builtin(__builtin_amdgcn_exp2f)
    return __builtin_amdgcn_exp2f(x);
#else
    return exp2f(x);
#endif
}
__device__ __forceinline__ float frcp(float x){
#if __has_builtin(__builtin_amdgcn_rcpf)
    return __builtin_amdgcn_rcpf(x);
#else
    return 1.f/x;
#endif
}
__device__ __forceinline__ float fsigmoid(float x){ return frcp(1.f + fexp2(-LOG2E*x)); }
__device__ __forceinline__ f32x4_t exp4(f32x4_t v){
    f32x4_t e; e[0]=fexp2(v[0]); e[1]=fexp2(v[1]); e[2]=fexp2(v[2]); e[3]=fexp2(v[3]); return e;
}
__device__ __forceinline__ f32x4_t rcp4(f32x4_t v){
    f32x4_t r; r[0]=frcp(v[0]); r[1]=frcp(v[1]); r[2]=frcp(v[2]); r[3]=frcp(v[3]); return r;
}

// pack two f32 -> one u32 of 2 bf16 (lo in bits 15:0)
__device__ __forceinline__ uint32_t pk_bf16(float lo, float hi){
    uint32_t r;
    asm("v_cvt_pk_bf16_f32 %0, %1, %2" : "=v"(r) : "v"(lo), "v"(hi));
    return r;
}

// Accs arrive pre-scaled into exp2 domain (scale folded into weights/biases):
//   aI,aF,aO = -LOG2E*z ; aG = +2*LOG2E*z
// Merged-rcp activation: 7 trans per element (5 exp + 2 rcp).
__device__ __forceinline__ f32x4_t lstm_act(f32x4_t aI, f32x4_t aF, f32x4_t aG,
                                            f32x4_t aO, f32x4_t& cst){
    f32x4_t eI = exp4(aI);
    f32x4_t eF = exp4(aF);
    f32x4_t eG = exp4(aG);
    f32x4_t eO = exp4(aO);
    f32x4_t D1 = eF + 1.f;
    f32x4_t tG = eG + 1.f;
    f32x4_t D2 = eI*tG + tG;           // (1+eI)(1+eG)
    f32x4_t r  = rcp4(D1*D2);
    f32x4_t f  = r*D2;                 // sigmoid(zf)
    f32x4_t p  = (eG - 1.f) * (r*D1);  // i*tanh(zg)
    cst = f*cst + p;
    f32x4_t cc;                        // clamp so e^{2c} can't overflow
    cc[0]=fminf(fmaxf(cst[0],-30.f),30.f);
    cc[1]=fminf(fmaxf(cst[1],-30.f),30.f);
    cc[2]=fminf(fmaxf(cst[2],-30.f),30.f);
    cc[3]=fminf(fmaxf(cst[3],-30.f),30.f);
    f32x4_t eC = exp4(cc * (2.f*LOG2E));
    f32x4_t tC = eC + 1.f;
    f32x4_t dn = eO*tC + tC;           // (1+eO)(1+eC)
    return (eC - 1.f) * rcp4(dn);
}

// R6: single-wave register-resident 2-layer LSTM.
// One 64-thread wave owns 16 batch rows x both layers. Swapped-operand MFMA:
//   gates[u][r] = sum_k W[u][k] * h[r][k]   (A = weight frag, B = h frag)
// B-frag layout (lane n=r, q): h[r][k=q*8+j]. D layout: col r=n, rows u=q4+reg.
// The D->B transpose for the next step is in-wave: cvt_pk + 8x2 ds_bpermute
// (src lane for words {0,1} = n+32*(q&1), words {2,3} = +16; half0 regs for
// q<2, half1 for q>=2). x0,x1 ride in B-frag k-slots 30,31; x2 via C-operand.
// NO LDS, NO barrier, NO flags, NO vmcnt drain anywhere in the 256-step loop.
__global__ __launch_bounds__(64, 1)
void lstm_fused(const float* __restrict__ x,
    const float* __restrict__ Wih0, const float* __restrict__ Whh0,
    const float* __restrict__ bih0, const float* __restrict__ bhh0,
    const float* __restrict__ Wih1, const float* __restrict__ Whh1,
    const float* __restrict__ bih1, const float* __restrict__ bhh1,
    const float* __restrict__ Wfc1, const float* __restrict__ bfc1,
    const float* __restrict__ Wfc2, const float* __restrict__ bfc2,
    const float* __restrict__ Wfc3, const float* __restrict__ bfc3,
    float* __restrict__ out)
{
    __shared__ float h1_last[16][32];
    __shared__ float zbuf[16][64];
    __shared__ float z2buf[16][32];

    const int lane = threadIdx.x;      // 0..63
    const int n    = lane & 15;
    const int q    = lane >> 4;
    const int q4   = q*4;
    const int bbase = blockIdx.x * 16;

    // ---- resident weight A-frags + per-D-row bias/x-weight vectors ----
    bf16x8_t w0[4][2], wi1[4][2], wh1[4][2];
    f32x4_t  bq0[4][2], wxq[4][2], bq1[4][2];
    {
        const float scl[4] = {-LOG2E, -LOG2E, 2.f*LOG2E, -LOG2E}; // i,f,g,o
        #pragma unroll
        for (int g = 0; g < 4; ++g) {
            #pragma unroll
            for (int ch = 0; ch < 2; ++ch) {
                const float sg = scl[g];
                {   // frag rows: u_f = ch*16 + n  (lane supplies W-row u_f)
                    const int uf = ch*16 + n;
                    const int uq = (uf < HID) ? uf : 0;   // garbage rows -> row0 (finite)
                    const int row = g*HID + uq;
                    bf16x8_t a{}, b{}, c{};
                    #pragma unroll
                    for (int j = 0; j < 8; ++j) {
                        const int k = q*8 + j;
                        float va=0.f, vb=0.f, vc=0.f;
                        if (k < HID) {
                            va = Whh0[row*HID + k];
                            vb = Wih1[row*HID + k];
                            vc = Whh1[row*HID + k];
                        } else if (k == 30) { va = Wih0[row*3 + 0]; }
                        else                { va = Wih0[row*3 + 1]; }
                        a[j]=(__bf16)(sg*va); b[j]=(__bf16)(sg*vb); c[j]=(__bf16)(sg*vc);
                    }
                    w0[g][ch]=a; wi1[g][ch]=b; wh1[g][ch]=c;
                }
                // bias / x2-weight per D-row: u_b = ch*16 + q4 + r
                f32x4_t b0v, wxv, b1v;
                #pragma unroll
                for (int r = 0; r < 4; ++r) {
                    const int ub = ch*16 + q4 + r;
                    const int uq = (ub < HID) ? ub : 0;
                    const int row = g*HID + uq;
                    b0v[r] = sg*(bih0[row] + bhh0[row]);
                    wxv[r] = sg*Wih0[row*3 + 2];
                    b1v[r] = sg*(bih1[row] + bhh1[row]);
                }
                bq0[g][ch]=b0v; wxq[g][ch]=wxv; bq1[g][ch]=b1v;
            }
        }
    }

    // ---- x prefetch ring (4 slots, static-indexed), global loads only ----
    const float* xr = x + (size_t)(bbase + n) * (TT*3);
    float px0[4], px1[4], px2[4];
    #pragma unroll
    for (int i = 0; i < 4; ++i) { px0[i]=xr[3*i]; px1[i]=xr[3*i+1]; px2[i]=xr[3*i+2]; }

    // transpose constants
    const int  ad01 = 4*(n + 32*(q & 1));
    const int  ad23 = ad01 + 64;
    const bool qlo  = (q < 2);
    const bool q3   = (q == 3);

    // state
    bf16x8_t h0frag, h1frag;
    {
        u32x4_t z = {0u,0u,0u,0u};
        if (q3) z[3] = pk_bf16(px0[0], px1[0]);   // x0,x1(t=0) in k-slots 30,31
        h0frag = __builtin_bit_cast(bf16x8_t, z);
        u32x4_t z1 = {0u,0u,0u,0u};
        h1frag = __builtin_bit_cast(bf16x8_t, z1);
    }
    f32x4_t c0A={0,0,0,0}, c0B={0,0,0,0}, c1A={0,0,0,0}, c1B={0,0,0,0};

#define MF(A,B,C) __builtin_amdgcn_mfma_f32_16x16x32_bf16((A),(B),(C),0,0,0)
#define BP(a,s)   ((uint32_t)__builtin_amdgcn_ds_bpermute((a),(int)(s)))

    // D(col r=n, rows u per half) -> next B-frag(h[r=n][k]); XW = k30,31 word for q==3
#define XPOSE(hA, hB, XW, dst) do {                                            \
    uint32_t a01=pk_bf16((hA)[0],(hA)[1]), a23=pk_bf16((hA)[2],(hA)[3]);       \
    uint32_t b01=pk_bf16((hB)[0],(hB)[1]), b23=pk_bf16((hB)[2],(hB)[3]);       \
    uint32_t t0a=BP(ad01,a01), t1a=BP(ad01,a23), t2a=BP(ad23,a01), t3a=BP(ad23,a23); \
    uint32_t t0b=BP(ad01,b01), t1b=BP(ad01,b23), t2b=BP(ad23,b01), t3b=BP(ad23,b23); \
    u32x4_t fw;                                                                \
    fw[0] = qlo ? t0a : t0b;                                                   \
    fw[1] = qlo ? t1a : t1b;                                                   \
    fw[2] = qlo ? t2a : t2b;                                                   \
    fw[3] = q3 ? (XW) : (qlo ? t3a : t3b);                                     \
    (dst) = __builtin_bit_cast(bf16x8_t, fw);                                  \
} while (0)

#define STEP(S, SA, SB) do {                                                   \
    const float x2v = px2[SA];                                                 \
    /* layer-0 gates: 8 MFMAs, C = bias + wx2*x2 */                            \
    f32x4_t aI0 = MF(w0[0][0], h0frag, bq0[0][0] + wxq[0][0]*x2v);             \
    f32x4_t aF0 = MF(w0[1][0], h0frag, bq0[1][0] + wxq[1][0]*x2v);             \
    f32x4_t aG0 = MF(w0[2][0], h0frag, bq0[2][0] + wxq[2][0]*x2v);             \
    f32x4_t aO0 = MF(w0[3][0], h0frag, bq0[3][0] + wxq[3][0]*x2v);             \
    f32x4_t aI1 = MF(w0[0][1], h0frag, bq0[0][1] + wxq[0][1]*x2v);             \
    f32x4_t aF1 = MF(w0[1][1], h0frag, bq0[1][1] + wxq[1][1]*x2v);             \
    f32x4_t aG1 = MF(w0[2][1], h0frag, bq0[2][1] + wxq[2][1]*x2v);             \
    f32x4_t aO1 = MF(w0[3][1], h0frag, bq0[3][1] + wxq[3][1]*x2v);             \
    /* layer-1 Whh1 half (old h1frag) - independent of layer-0, fills bubbles */ \
    f32x4_t dI0 = MF(wh1[0][0], h1frag, bq1[0][0]);                            \
    f32x4_t dF0 = MF(wh1[1][0], h1frag, bq1[1][0]);                            \
    f32x4_t dG0 = MF(wh1[2][0], h1frag, bq1[2][0]);                            \
    f32x4_t dO0 = MF(wh1[3][0], h1frag, bq1[3][0]);                            \
    f32x4_t dI1 = MF(wh1[0][1], h1frag, bq1[0][1]);                            \
    f32x4_t dF1 = MF(wh1[1][1], h1frag, bq1[1][1]);                            \
    f32x4_t dG1 = MF(wh1[2][1], h1frag, bq1[2][1]);                            \
    f32x4_t dO1 = MF(wh1[3][1], h1frag, bq1[3][1]);                            \
    f32x4_t h0A = lstm_act(aI0,aF0,aG0,aO0,c0A);                               \
    f32x4_t h0B = lstm_act(aI1,aF1,aG1,aO1,c0B);                               \
    XPOSE(h0A, h0B, pk_bf16(px0[SB], px1[SB]), h0frag);   /* h0(t) + x01(t+1) */ \
    /* layer-1 Wih1 half on the NEW h0frag (k30,31 weights are 0) */           \
    dI0 = MF(wi1[0][0], h0frag, dI0);  dF0 = MF(wi1[1][0], h0frag, dF0);       \
    dG0 = MF(wi1[2][0], h0frag, dG0);  dO0 = MF(wi1[3][0], h0frag, dO0);       \
    dI1 = MF(wi1[0][1], h0frag, dI1);  dF1 = MF(wi1[1][1], h0frag, dF1);       \
    dG1 = MF(wi1[2][1], h0frag, dG1);  dO1 = MF(wi1[3][1], h0frag, dO1);       \
    f32x4_t h1A = lstm_act(dI0,dF0,dG0,dO0,c1A);                               \
    f32x4_t h1B = lstm_act(dI1,dF1,dG1,dO1,c1B);                               \
    if ((S) == TT-1) {                                                         \
        *(f32x4_t*)&h1_last[n][q4]    = h1A;                                   \
        *(f32x4_t*)&h1_last[n][16+q4] = h1B;                                   \
    } else {                                                                   \
        XPOSE(h1A, h1B, 0u, h1frag);                                           \
    }                                                                          \
    { const int tp = ((S)+4 < TT) ? (S)+4 : TT-1;                              \
      px0[SA]=xr[3*tp]; px1[SA]=xr[3*tp+1]; px2[SA]=xr[3*tp+2]; }              \
} while (0)

    #pragma unroll 1
    for (int s = 0; s < TT; s += 4) {
        STEP(s+0, 0, 1);
        STEP(s+1, 1, 2);
        STEP(s+2, 2, 3);
        STEP(s+3, 3, 0);
    }
#undef STEP
#undef XPOSE
#undef BP
#undef MF

    __syncthreads();

    // ---- FC head (1 wave, 16 rows) ----
    #pragma unroll 1
    for (int m = 0; m < 16; ++m) {
        float a = bfc1[lane];
        for (int k = 0; k < HID; ++k) a += h1_last[m][k] * Wfc1[lane*HID+k];
        zbuf[m][lane] = fmaxf(a, 0.f);
    }
    __syncthreads();
    #pragma unroll 1
    for (int rep = 0; rep < 8; ++rep) {
        int idx = lane + rep*64;          // 16*32 outputs
        int m = idx >> 5, v = idx & 31;
        float a = bfc2[v];
        for (int k = 0; k < 64; ++k) a += zbuf[m][k] * Wfc2[v*64+k];
        z2buf[m][v] = fmaxf(a, 0.f);
    }
    __syncthreads();
    if (lane < 16) {
        float a = bfc3[0];
        for (int k = 0; k < 32; ++k) a += z2buf[lane][k] * Wfc3[k];
        out[bbase + lane] = fsigmoid(a);
    }
}

extern "C" void kernel_launch(void* const* d_in, const int* in_sizes, int n_in,
                              void* d_out, int out_size, void* d_ws, size_t ws_size,
                              hipStream_t stream) {
    const float* x    = (const float*)d_in[0];
    const float* Wih0 = (const float*)d_in[1];
    const float* Whh0 = (const float*)d_in[2];
    const float* bih0 = (const float*)d_in[3];
    const float* bhh0 = (const float*)d_in[4];
    const float* Wih1 = (const float*)d_in[5];
    const float* Whh1 = (const float*)d_in[6];
    const float* bih1 = (const float*)d_in[7];
    const float* bhh1 = (const float*)d_in[8];
    const float* Wfc1 = (const float*)d_in[9];
    const float* bfc1 = (const float*)d_in[10];
    const float* Wfc2 = (const float*)d_in[11];
    const float* bfc2 = (const float*)d_in[12];
    const float* Wfc3 = (const float*)d_in[13];
    const float* bfc3 = (const float*)d_in[14];
    float* outp = (float*)d_out;

    hipLaunchKernelGGL(lstm_fused, dim3(512), dim3(64), 0, stream,
        x, Wih0, Whh0, bih0, bhh0, Wih1, Whh1, bih1, bhh1,
        Wfc1, bfc1, Wfc2, bfc2, Wfc3, bfc3, outp);
}

// Round 7
// 307.811 us; speedup vs baseline: 1.3199x; 1.3199x over previous
//
#include <hip/hip_runtime.h>

#define TT   256
#define HID  30
#define LOG2E 1.4426950408889634f
#define HS   40   // ring row stride (bf16)
#define NR   16   // ring slots (one-way L0->L1 pipe)

typedef __bf16 bf16x8_t __attribute__((ext_vector_type(8)));
typedef float  f32x4_t  __attribute__((ext_vector_type(4)));
typedef unsigned int u32x4_t __attribute__((ext_vector_type(4)));

__device__ __forceinline__ float fexp2(float x){
#if __has_builtin(__builtin_amdgcn_exp2f)
    return __builtin_amdgcn_exp2f(x);
#else
    return exp2f(x);
#endif
}
__device__ __forceinline__ float frcp(float x){
#if __has_builtin(__builtin_amdgcn_rcpf)
    return __builtin_amdgcn_rcpf(x);
#else
    return 1.f/x;
#endif
}
__device__ __forceinline__ float fsigmoid(float x){ return frcp(1.f + fexp2(-LOG2E*x)); }
__device__ __forceinline__ f32x4_t exp4(f32x4_t v){
    f32x4_t e; e[0]=fexp2(v[0]); e[1]=fexp2(v[1]); e[2]=fexp2(v[2]); e[3]=fexp2(v[3]); return e;
}
__device__ __forceinline__ f32x4_t rcp4(f32x4_t v){
    f32x4_t r; r[0]=frcp(v[0]); r[1]=frcp(v[1]); r[2]=frcp(v[2]); r[3]=frcp(v[3]); return r;
}

__device__ __forceinline__ uint32_t pk_bf16(float lo, float hi){
    uint32_t r;
    asm("v_cvt_pk_bf16_f32 %0, %1, %2" : "=v"(r) : "v"(lo), "v"(hi));
    return r;
}

__device__ __forceinline__ int ld_acq(int* p){
    return __hip_atomic_load(p, __ATOMIC_ACQUIRE, __HIP_MEMORY_SCOPE_WORKGROUP);
}
__device__ __forceinline__ void st_rel(int* p, int v){
    __hip_atomic_store(p, v, __ATOMIC_RELEASE, __HIP_MEMORY_SCOPE_WORKGROUP);
}

// Accs arrive pre-scaled into exp2 domain (scale folded into weights/biases):
//   aI,aF,aO = -LOG2E*z ; aG = +2*LOG2E*z
// Merged-rcp activation: 28 trans insts (20 exp + 8 rcp) per 4-vec.
__device__ __forceinline__ f32x4_t lstm_act(f32x4_t aI, f32x4_t aF, f32x4_t aG,
                                            f32x4_t aO, f32x4_t& cst){
    f32x4_t eI = exp4(aI);
    f32x4_t eF = exp4(aF);
    f32x4_t eG = exp4(aG);
    f32x4_t eO = exp4(aO);
    f32x4_t D1 = eF + 1.f;
    f32x4_t tG = eG + 1.f;
    f32x4_t D2 = eI*tG + tG;           // (1+eI)(1+eG)
    f32x4_t r  = rcp4(D1*D2);
    f32x4_t f  = r*D2;                 // sigmoid(zf)
    f32x4_t p  = (eG - 1.f) * (r*D1);  // i*tanh(zg)
    cst = f*cst + p;
    f32x4_t cc;                        // clamp so e^{2c} can't overflow
    cc[0]=fminf(fmaxf(cst[0],-30.f),30.f);
    cc[1]=fminf(fmaxf(cst[1],-30.f),30.f);
    cc[2]=fminf(fmaxf(cst[2],-30.f),30.f);
    cc[3]=fminf(fmaxf(cst[3],-30.f),30.f);
    f32x4_t eC = exp4(cc * (2.f*LOG2E));
    f32x4_t tC = eC + 1.f;
    f32x4_t dn = eO*tC + tC;           // (1+eO)(1+eC)
    return (eC - 1.f) * rcp4(dn);
}

// R7: decoupled two-wave pipeline, register-resident recurrences.
// 128-thread block = {L0 wave, L1 wave} for 16 batch rows; grid 512 ->
// 2 blocks/CU, 4 waves/CU, ~1 wave/SIMD. Swapped-operand MFMA
// (gates[u][r] = W x h^T) with the R6-validated in-register D->B transpose
// (cvt_pk + 8 ds_bpermute) keeps each layer's h->h recurrence INSIDE its
// wave: no barrier, no cross-wave round-trip on the critical path.
// L0 -> L1 handoff: 16-slot LDS ring of post-transpose h0 fragments
// (1 ds_write_b128 per lane per step), seq/cons flags with amortized
// checks (L1 re-reads seq only when its cached grant is exhausted; L0
// checks cons only when >NR-4 ahead). x staged to LDS once; the loop is
// global-free so release stores only drain the wave's own few LDS ops.
__global__ __launch_bounds__(128, 1)
void lstm_fused(const float* __restrict__ x,
    const float* __restrict__ Wih0, const float* __restrict__ Whh0,
    const float* __restrict__ bih0, const float* __restrict__ bhh0,
    const float* __restrict__ Wih1, const float* __restrict__ Whh1,
    const float* __restrict__ bih1, const float* __restrict__ bhh1,
    const float* __restrict__ Wfc1, const float* __restrict__ bfc1,
    const float* __restrict__ Wfc2, const float* __restrict__ bfc2,
    const float* __restrict__ Wfc3, const float* __restrict__ bfc3,
    float* __restrict__ out)
{
    __shared__ __align__(16) __bf16 ring[NR][16][HS];   // 20.5KB
    __shared__ __align__(4)  __bf16 xlds01[TT+1][16][2];// 16.4KB (pad slot: zeros)
    __shared__ __align__(16) float  xlds2[TT][16];      // 16KB
    __shared__ float h1_last[16][32];
    __shared__ float zbuf[16][64];
    __shared__ float z2buf[16][32];
    __shared__ int   flags[2];     // 0 = seq (L0 steps done), 1 = cons (L1 steps done)

    const int tid  = threadIdx.x;
    const int lane = tid & 63;
    const int wv   = tid >> 6;     // 0 = L0 wave, 1 = L1 wave
    const int n    = lane & 15;
    const int q    = lane >> 4;
    const int q4   = q*4;
    const int bbase = blockIdx.x * 16;

    // ---- stage x into LDS (once); x0,x1 as packed bf16, x2 as f32 ----
    {
        const float* xg = x + (size_t)bbase*(TT*3);
        for (int i4 = tid*4; i4 < 16*TT*3; i4 += 128*4) {
            int row = i4 / (TT*3), tc0 = i4 % (TT*3);
            f32x4_t v = *(const f32x4_t*)(xg + (size_t)row*(TT*3) + tc0);
            #pragma unroll
            for (int j = 0; j < 4; ++j) {
                int tc = tc0 + j;
                int t = tc/3, c = tc - 3*t;
                if (c == 2) xlds2[t][row] = v[j];
                else        xlds01[t][row][c] = (__bf16)v[j];
            }
        }
        if (tid < 32) xlds01[TT][tid>>1][tid&1] = (__bf16)0.f;   // pad slot
        if (tid == 0) { flags[0]=0; flags[1]=0; }
    }

    // transpose constants (R6-validated mapping)
    const int  ad01 = 4*(n + 32*(q & 1));
    const int  ad23 = ad01 + 64;
    const bool qlo  = (q < 2);
    const bool q3   = (q == 3);

    __syncthreads();

#define MF(A,B,C) __builtin_amdgcn_mfma_f32_16x16x32_bf16((A),(B),(C),0,0,0)
#define BP(a,s)   ((uint32_t)__builtin_amdgcn_ds_bpermute((a),(int)(s)))
#define XPOSE(hA, hB, XW, dst) do {                                            \
    uint32_t a01=pk_bf16((hA)[0],(hA)[1]), a23=pk_bf16((hA)[2],(hA)[3]);       \
    uint32_t b01=pk_bf16((hB)[0],(hB)[1]), b23=pk_bf16((hB)[2],(hB)[3]);       \
    uint32_t t0a=BP(ad01,a01), t1a=BP(ad01,a23), t2a=BP(ad23,a01), t3a=BP(ad23,a23); \
    uint32_t t0b=BP(ad01,b01), t1b=BP(ad01,b23), t2b=BP(ad23,b01), t3b=BP(ad23,b23); \
    u32x4_t fw;                                                                \
    fw[0] = qlo ? t0a : t0b;                                                   \
    fw[1] = qlo ? t1a : t1b;                                                   \
    fw[2] = qlo ? t2a : t2b;                                                   \
    fw[3] = q3 ? (XW) : (qlo ? t3a : t3b);                                     \
    (dst) = __builtin_bit_cast(bf16x8_t, fw);                                  \
} while (0)

    const float scl[4] = {-LOG2E, -LOG2E, 2.f*LOG2E, -LOG2E}; // i,f,g,o

    if (wv == 0) {
        // =========================== LAYER-0 wave ===========================
        bf16x8_t w0[4][2];
        f32x4_t  bq0[4][2], wxq[4][2];
        #pragma unroll
        for (int g = 0; g < 4; ++g) {
            #pragma unroll
            for (int ch = 0; ch < 2; ++ch) {
                const float sg = scl[g];
                const int uf = ch*16 + n;
                const int uqf = (uf < HID) ? uf : 0;
                const int rowf = g*HID + uqf;
                bf16x8_t a{};
                #pragma unroll
                for (int j = 0; j < 8; ++j) {
                    const int k = q*8 + j;
                    float va;
                    if (k < HID)       va = Whh0[rowf*HID + k];
                    else if (k == 30)  va = Wih0[rowf*3 + 0];
                    else               va = Wih0[rowf*3 + 1];
                    a[j] = (__bf16)(sg*va);
                }
                w0[g][ch] = a;
                f32x4_t b0v, wxv;
                #pragma unroll
                for (int r = 0; r < 4; ++r) {
                    const int ub = ch*16 + q4 + r;
                    const int uqb = (ub < HID) ? ub : 0;
                    const int rowb = g*HID + uqb;
                    b0v[r] = sg*(bih0[rowb] + bhh0[rowb]);
                    wxv[r] = sg*Wih0[rowb*3 + 2];
                }
                bq0[g][ch] = b0v;  wxq[g][ch] = wxv;
            }
        }

        bf16x8_t h0frag;
        {
            u32x4_t z = {0u,0u,0u,0u};
            if (q3) z[3] = *(const uint32_t*)&xlds01[0][n][0];   // x01(t=0)
            h0frag = __builtin_bit_cast(bf16x8_t, z);
        }
        f32x4_t c0A = {0,0,0,0}, c0B = {0,0,0,0};
        int consv = 0;

        #pragma unroll 1
        for (int s = 0; s < TT; ++s) {
            if (s - consv > NR-4) {                       // rare: L1 far behind
                do { consv = ld_acq(&flags[1]); } while (s - consv > NR-1);
            }
            const float x2v = xlds2[s][n];
            f32x4_t aI0 = MF(w0[0][0], h0frag, bq0[0][0] + wxq[0][0]*x2v);
            f32x4_t aF0 = MF(w0[1][0], h0frag, bq0[1][0] + wxq[1][0]*x2v);
            f32x4_t aG0 = MF(w0[2][0], h0frag, bq0[2][0] + wxq[2][0]*x2v);
            f32x4_t aO0 = MF(w0[3][0], h0frag, bq0[3][0] + wxq[3][0]*x2v);
            f32x4_t aI1 = MF(w0[0][1], h0frag, bq0[0][1] + wxq[0][1]*x2v);
            f32x4_t aF1 = MF(w0[1][1], h0frag, bq0[1][1] + wxq[1][1]*x2v);
            f32x4_t aG1 = MF(w0[2][1], h0frag, bq0[2][1] + wxq[2][1]*x2v);
            f32x4_t aO1 = MF(w0[3][1], h0frag, bq0[3][1] + wxq[3][1]*x2v);
            f32x4_t h0A = lstm_act(aI0, aF0, aG0, aO0, c0A);
            f32x4_t h0B = lstm_act(aI1, aF1, aG1, aO1, c0B);
            const uint32_t XW = *(const uint32_t*)&xlds01[s+1][n][0]; // x01(t+1)
            XPOSE(h0A, h0B, XW, h0frag);
            *(bf16x8_t*)&ring[s & (NR-1)][n][q*8] = h0frag;   // publish h0(t)
            if (lane == 0) st_rel(&flags[0], s+1);
        }
    } else {
        // =========================== LAYER-1 wave ===========================
        bf16x8_t wi1[4][2], wh1[4][2];
        f32x4_t  bq1[4][2];
        #pragma unroll
        for (int g = 0; g < 4; ++g) {
            #pragma unroll
            for (int ch = 0; ch < 2; ++ch) {
                const float sg = scl[g];
                const int uf = ch*16 + n;
                const int uqf = (uf < HID) ? uf : 0;
                const int rowf = g*HID + uqf;
                bf16x8_t a{}, b{};
                #pragma unroll
                for (int j = 0; j < 8; ++j) {
                    const int k = q*8 + j;
                    float va = 0.f, vb = 0.f;
                    if (k < HID) { va = Wih1[rowf*HID + k];  vb = Whh1[rowf*HID + k]; }
                    a[j] = (__bf16)(sg*va);
                    b[j] = (__bf16)(sg*vb);
                }
                wi1[g][ch] = a;  wh1[g][ch] = b;
                f32x4_t b1v;
                #pragma unroll
                for (int r = 0; r < 4; ++r) {
                    const int ub = ch*16 + q4 + r;
                    const int uqb = (ub < HID) ? ub : 0;
                    const int rowb = g*HID + uqb;
                    b1v[r] = sg*(bih1[rowb] + bhh1[rowb]);
                }
                bq1[g][ch] = b1v;
            }
        }

        bf16x8_t h1frag;
        { u32x4_t z = {0u,0u,0u,0u}; h1frag = __builtin_bit_cast(bf16x8_t, z); }
        f32x4_t c1A = {0,0,0,0}, c1B = {0,0,0,0};
        int seqv = 0;

        #pragma unroll 1
        for (int s = 0; s < TT; ++s) {
            if (seqv < s+1) {                       // amortized: one grant covers many steps
                do { seqv = ld_acq(&flags[0]); } while (seqv < s+1);
            }
            __builtin_amdgcn_sched_barrier(0);      // keep ds_read below the acquire
            bf16x8_t A1 = *(const bf16x8_t*)&ring[s & (NR-1)][n][q*8];
            f32x4_t dI0 = MF(wi1[0][0], A1, bq1[0][0]);
            f32x4_t dF0 = MF(wi1[1][0], A1, bq1[1][0]);
            f32x4_t dG0 = MF(wi1[2][0], A1, bq1[2][0]);
            f32x4_t dO0 = MF(wi1[3][0], A1, bq1[3][0]);
            f32x4_t dI1 = MF(wi1[0][1], A1, bq1[0][1]);
            f32x4_t dF1 = MF(wi1[1][1], A1, bq1[1][1]);
            f32x4_t dG1 = MF(wi1[2][1], A1, bq1[2][1]);
            f32x4_t dO1 = MF(wi1[3][1], A1, bq1[3][1]);
            dI0 = MF(wh1[0][0], h1frag, dI0);
            dF0 = MF(wh1[1][0], h1frag, dF0);
            dG0 = MF(wh1[2][0], h1frag, dG0);
            dO0 = MF(wh1[3][0], h1frag, dO0);
            dI1 = MF(wh1[0][1], h1frag, dI1);
            dF1 = MF(wh1[1][1], h1frag, dF1);
            dG1 = MF(wh1[2][1], h1frag, dG1);
            dO1 = MF(wh1[3][1], h1frag, dO1);
            f32x4_t h1A = lstm_act(dI0, dF0, dG0, dO0, c1A);
            f32x4_t h1B = lstm_act(dI1, dF1, dG1, dO1, c1B);
            if (s == TT-1) {
                *(f32x4_t*)&h1_last[n][q4]    = h1A;
                *(f32x4_t*)&h1_last[n][16+q4] = h1B;
            } else {
                XPOSE(h1A, h1B, 0u, h1frag);
            }
            if (((s & 3) == 3) && lane == 0) st_rel(&flags[1], s+1);
        }
    }
#undef XPOSE
#undef BP
#undef MF

    __syncthreads();

    // ---- FC head (128 threads, 16 rows) ----
    #pragma unroll
    for (int rep = 0; rep < 8; ++rep) {
        int idx = tid + rep*128;          // 16*64 outputs
        int m = idx >> 6, uu = idx & 63;
        float a = bfc1[uu];
        for (int k = 0; k < HID; ++k) a += h1_last[m][k] * Wfc1[uu*HID+k];
        zbuf[m][uu] = fmaxf(a, 0.f);
    }
    __syncthreads();
    #pragma unroll
    for (int rep = 0; rep < 4; ++rep) {
        int idx = tid + rep*128;          // 16*32 outputs
        int m = idx >> 5, v = idx & 31;
        float a = bfc2[v];
        for (int k = 0; k < 64; ++k) a += zbuf[m][k] * Wfc2[v*64+k];
        z2buf[m][v] = fmaxf(a, 0.f);
    }
    __syncthreads();
    if (tid < 16) {
        float a = bfc3[0];
        for (int k = 0; k < 32; ++k) a += z2buf[tid][k] * Wfc3[k];
        out[bbase + tid] = fsigmoid(a);
    }
}

extern "C" void kernel_launch(void* const* d_in, const int* in_sizes, int n_in,
                              void* d_out, int out_size, void* d_ws, size_t ws_size,
                              hipStream_t stream) {
    const float* x    = (const float*)d_in[0];
    const float* Wih0 = (const float*)d_in[1];
    const float* Whh0 = (const float*)d_in[2];
    const float* bih0 = (const float*)d_in[3];
    const float* bhh0 = (const float*)d_in[4];
    const float* Wih1 = (const float*)d_in[5];
    const float* Whh1 = (const float*)d_in[6];
    const float* bih1 = (const float*)d_in[7];
    const float* bhh1 = (const float*)d_in[8];
    const float* Wfc1 = (const float*)d_in[9];
    const float* bfc1 = (const float*)d_in[10];
    const float* Wfc2 = (const float*)d_in[11];
    const float* bfc2 = (const float*)d_in[12];
    const float* Wfc3 = (const float*)d_in[13];
    const float* bfc3 = (const float*)d_in[14];
    float* outp = (float*)d_out;

    hipLaunchKernelGGL(lstm_fused, dim3(512), dim3(128), 0, stream,
        x, Wih0, Whh0, bih0, bhh0, Wih1, Whh1, bih1, bhh1,
        Wfc1, bfc1, Wfc2, bfc2, Wfc3, bfc3, outp);
}

// Round 8
// 285.619 us; speedup vs baseline: 1.4225x; 1.0777x over previous
//
#include <hip/hip_runtime.h>

#define TT    256
#define HID   30
#define LOG2E 1.4426950408889634f
#define HS    40   // ring row stride (bf16)
#define NR    16   // ring slots = 2 chunks (double buffer)
#define CHUNK 8

typedef __bf16 bf16x8_t __attribute__((ext_vector_type(8)));
typedef float  f32x4_t  __attribute__((ext_vector_type(4)));
typedef unsigned int u32x4_t __attribute__((ext_vector_type(4)));

__device__ __forceinline__ float fexp2(float x){
#if __has_builtin(__builtin_amdgcn_exp2f)
    return __builtin_amdgcn_exp2f(x);
#else
    return exp2f(x);
#endif
}
__device__ __forceinline__ float frcp(float x){
#if __has_builtin(__builtin_amdgcn_rcpf)
    return __builtin_amdgcn_rcpf(x);
#else
    return 1.f/x;
#endif
}
__device__ __forceinline__ float fsigmoid(float x){ return frcp(1.f + fexp2(-LOG2E*x)); }
__device__ __forceinline__ f32x4_t exp4(f32x4_t v){
    f32x4_t e; e[0]=fexp2(v[0]); e[1]=fexp2(v[1]); e[2]=fexp2(v[2]); e[3]=fexp2(v[3]); return e;
}
__device__ __forceinline__ f32x4_t rcp4(f32x4_t v){
    f32x4_t r; r[0]=frcp(v[0]); r[1]=frcp(v[1]); r[2]=frcp(v[2]); r[3]=frcp(v[3]); return r;
}

__device__ __forceinline__ uint32_t pk_bf16(float lo, float hi){
    uint32_t r;
    asm("v_cvt_pk_bf16_f32 %0, %1, %2" : "=v"(r) : "v"(lo), "v"(hi));
    return r;
}

// Accs arrive pre-scaled into exp2 domain (scale folded into weights/biases):
//   aI,aF,aO = -LOG2E*z ; aG = +2*LOG2E*z
// Merged-rcp activation: 28 trans insts (20 exp + 8 rcp) per 4-vec.
__device__ __forceinline__ f32x4_t lstm_act(f32x4_t aI, f32x4_t aF, f32x4_t aG,
                                            f32x4_t aO, f32x4_t& cst){
    f32x4_t eI = exp4(aI);
    f32x4_t eF = exp4(aF);
    f32x4_t eG = exp4(aG);
    f32x4_t eO = exp4(aO);
    f32x4_t D1 = eF + 1.f;
    f32x4_t tG = eG + 1.f;
    f32x4_t D2 = eI*tG + tG;           // (1+eI)(1+eG)
    f32x4_t r  = rcp4(D1*D2);
    f32x4_t f  = r*D2;                 // sigmoid(zf)
    f32x4_t p  = (eG - 1.f) * (r*D1);  // i*tanh(zg)
    cst = f*cst + p;
    f32x4_t cc;                        // clamp so e^{2c} can't overflow
    cc[0]=fminf(fmaxf(cst[0],-30.f),30.f);
    cc[1]=fminf(fmaxf(cst[1],-30.f),30.f);
    cc[2]=fminf(fmaxf(cst[2],-30.f),30.f);
    cc[3]=fminf(fmaxf(cst[3],-30.f),30.f);
    f32x4_t eC = exp4(cc * (2.f*LOG2E));
    f32x4_t tC = eC + 1.f;
    f32x4_t dn = eO*tC + tC;           // (1+eO)(1+eC)
    return (eC - 1.f) * rcp4(dn);
}

// R8: chunked producer/consumer with register-resident recurrences.
// 128-thread block = {L0 wave, L1 wave}, 16 batch rows; grid 512.
// Each wave's own h->h recurrence is IN REGISTERS (cvt_pk + ds_bpermute
// transpose, R6/R7-validated) -> zero sync for 8 consecutive steps.
// L0 writes its 8 post-transpose h0 fragments into ring slots; ONE
// __syncthreads per chunk publishes them; L1 consumes chunk c-1 while
// L0 produces chunk c (16-slot ring = double buffer). Sync cost ~1/8
// of R4's per-step barrier; no flags, no atomics, no spins. The loop
// is global-free (x staged to LDS once), so the barrier drain is cheap.
__global__ __launch_bounds__(128, 1)
void lstm_fused(const float* __restrict__ x,
    const float* __restrict__ Wih0, const float* __restrict__ Whh0,
    const float* __restrict__ bih0, const float* __restrict__ bhh0,
    const float* __restrict__ Wih1, const float* __restrict__ Whh1,
    const float* __restrict__ bih1, const float* __restrict__ bhh1,
    const float* __restrict__ Wfc1, const float* __restrict__ bfc1,
    const float* __restrict__ Wfc2, const float* __restrict__ bfc2,
    const float* __restrict__ Wfc3, const float* __restrict__ bfc3,
    float* __restrict__ out)
{
    __shared__ __align__(16) __bf16 ring[NR][16][HS];    // 20.5KB
    __shared__ __align__(4)  __bf16 xlds01[TT+1][16][2]; // 16.4KB (pad slot zeros)
    __shared__ __align__(16) float  xlds2[TT][16];       // 16KB
    __shared__ float h1_last[16][32];
    __shared__ float zbuf[16][64];
    __shared__ float z2buf[16][32];

    const int tid  = threadIdx.x;
    const int lane = tid & 63;
    const int wv   = tid >> 6;     // 0 = L0 wave, 1 = L1 wave
    const int n    = lane & 15;
    const int q    = lane >> 4;
    const int q4   = q*4;
    const int bbase = blockIdx.x * 16;

    // ---- stage x into LDS (once); x0,x1 as packed bf16, x2 as f32 ----
    {
        const float* xg = x + (size_t)bbase*(TT*3);
        for (int i4 = tid*4; i4 < 16*TT*3; i4 += 128*4) {
            int row = i4 / (TT*3), tc0 = i4 % (TT*3);
            f32x4_t v = *(const f32x4_t*)(xg + (size_t)row*(TT*3) + tc0);
            #pragma unroll
            for (int j = 0; j < 4; ++j) {
                int tc = tc0 + j;
                int t = tc/3, c = tc - 3*t;
                if (c == 2) xlds2[t][row] = v[j];
                else        xlds01[t][row][c] = (__bf16)v[j];
            }
        }
        if (tid < 32) xlds01[TT][tid>>1][tid&1] = (__bf16)0.f;   // pad slot
    }

    // transpose constants (R6/R7-validated mapping)
    const int  ad01 = 4*(n + 32*(q & 1));
    const int  ad23 = ad01 + 64;
    const bool qlo  = (q < 2);
    const bool q3   = (q == 3);

    __syncthreads();

#define MF(A,B,C) __builtin_amdgcn_mfma_f32_16x16x32_bf16((A),(B),(C),0,0,0)
#define BP(a,s)   ((uint32_t)__builtin_amdgcn_ds_bpermute((a),(int)(s)))
#define XPOSE(hA, hB, XW, dst) do {                                            \
    uint32_t a01=pk_bf16((hA)[0],(hA)[1]), a23=pk_bf16((hA)[2],(hA)[3]);       \
    uint32_t b01=pk_bf16((hB)[0],(hB)[1]), b23=pk_bf16((hB)[2],(hB)[3]);       \
    uint32_t t0a=BP(ad01,a01), t1a=BP(ad01,a23), t2a=BP(ad23,a01), t3a=BP(ad23,a23); \
    uint32_t t0b=BP(ad01,b01), t1b=BP(ad01,b23), t2b=BP(ad23,b01), t3b=BP(ad23,b23); \
    u32x4_t fw;                                                                \
    fw[0] = qlo ? t0a : t0b;                                                   \
    fw[1] = qlo ? t1a : t1b;                                                   \
    fw[2] = qlo ? t2a : t2b;                                                   \
    fw[3] = q3 ? (XW) : (qlo ? t3a : t3b);                                     \
    (dst) = __builtin_bit_cast(bf16x8_t, fw);                                  \
} while (0)

    const float scl[4] = {-LOG2E, -LOG2E, 2.f*LOG2E, -LOG2E}; // i,f,g,o

    if (wv == 0) {
        // =========================== LAYER-0 wave ===========================
        bf16x8_t w0[4][2];
        f32x4_t  bq0[4][2], wxq[4][2];
        #pragma unroll
        for (int g = 0; g < 4; ++g) {
            #pragma unroll
            for (int ch = 0; ch < 2; ++ch) {
                const float sg = scl[g];
                const int uf = ch*16 + n;
                const int uqf = (uf < HID) ? uf : 0;
                const int rowf = g*HID + uqf;
                bf16x8_t a{};
                #pragma unroll
                for (int j = 0; j < 8; ++j) {
                    const int k = q*8 + j;
                    float va;
                    if (k < HID)       va = Whh0[rowf*HID + k];
                    else if (k == 30)  va = Wih0[rowf*3 + 0];
                    else               va = Wih0[rowf*3 + 1];
                    a[j] = (__bf16)(sg*va);
                }
                w0[g][ch] = a;
                f32x4_t b0v, wxv;
                #pragma unroll
                for (int r = 0; r < 4; ++r) {
                    const int ub = ch*16 + q4 + r;
                    const int uqb = (ub < HID) ? ub : 0;
                    const int rowb = g*HID + uqb;
                    b0v[r] = sg*(bih0[rowb] + bhh0[rowb]);
                    wxv[r] = sg*Wih0[rowb*3 + 2];
                }
                bq0[g][ch] = b0v;  wxq[g][ch] = wxv;
            }
        }

        bf16x8_t h0frag;
        {
            u32x4_t z = {0u,0u,0u,0u};
            if (q3) z[3] = *(const uint32_t*)&xlds01[0][n][0];   // x01(t=0)
            h0frag = __builtin_bit_cast(bf16x8_t, z);
        }
        f32x4_t c0A = {0,0,0,0}, c0B = {0,0,0,0};

        #pragma unroll 1
        for (int c = 0; c <= TT/CHUNK; ++c) {
            if (c < TT/CHUNK) {
                const int sb   = c*CHUNK;
                const int half = (c & 1)*CHUNK;
                #pragma unroll
                for (int j = 0; j < CHUNK; ++j) {
                    const int s = sb + j;
                    const float x2v = xlds2[s][n];
                    f32x4_t aI0 = MF(w0[0][0], h0frag, bq0[0][0] + wxq[0][0]*x2v);
                    f32x4_t aF0 = MF(w0[1][0], h0frag, bq0[1][0] + wxq[1][0]*x2v);
                    f32x4_t aG0 = MF(w0[2][0], h0frag, bq0[2][0] + wxq[2][0]*x2v);
                    f32x4_t aO0 = MF(w0[3][0], h0frag, bq0[3][0] + wxq[3][0]*x2v);
                    f32x4_t aI1 = MF(w0[0][1], h0frag, bq0[0][1] + wxq[0][1]*x2v);
                    f32x4_t aF1 = MF(w0[1][1], h0frag, bq0[1][1] + wxq[1][1]*x2v);
                    f32x4_t aG1 = MF(w0[2][1], h0frag, bq0[2][1] + wxq[2][1]*x2v);
                    f32x4_t aO1 = MF(w0[3][1], h0frag, bq0[3][1] + wxq[3][1]*x2v);
                    f32x4_t h0A = lstm_act(aI0, aF0, aG0, aO0, c0A);
                    f32x4_t h0B = lstm_act(aI1, aF1, aG1, aO1, c0B);
                    const uint32_t XW = *(const uint32_t*)&xlds01[s+1][n][0];
                    XPOSE(h0A, h0B, XW, h0frag);
                    *(bf16x8_t*)&ring[half + j][n][q*8] = h0frag;   // publish h0(s)
                }
            }
            __syncthreads();
        }
    } else {
        // =========================== LAYER-1 wave ===========================
        bf16x8_t wi1[4][2], wh1[4][2];
        f32x4_t  bq1[4][2];
        #pragma unroll
        for (int g = 0; g < 4; ++g) {
            #pragma unroll
            for (int ch = 0; ch < 2; ++ch) {
                const float sg = scl[g];
                const int uf = ch*16 + n;
                const int uqf = (uf < HID) ? uf : 0;
                const int rowf = g*HID + uqf;
                bf16x8_t a{}, b{};
                #pragma unroll
                for (int j = 0; j < 8; ++j) {
                    const int k = q*8 + j;
                    float va = 0.f, vb = 0.f;
                    if (k < HID) { va = Wih1[rowf*HID + k];  vb = Whh1[rowf*HID + k]; }
                    a[j] = (__bf16)(sg*va);
                    b[j] = (__bf16)(sg*vb);
                }
                wi1[g][ch] = a;  wh1[g][ch] = b;
                f32x4_t b1v;
                #pragma unroll
                for (int r = 0; r < 4; ++r) {
                    const int ub = ch*16 + q4 + r;
                    const int uqb = (ub < HID) ? ub : 0;
                    const int rowb = g*HID + uqb;
                    b1v[r] = sg*(bih1[rowb] + bhh1[rowb]);
                }
                bq1[g][ch] = b1v;
            }
        }

        bf16x8_t h1frag;
        { u32x4_t z = {0u,0u,0u,0u}; h1frag = __builtin_bit_cast(bf16x8_t, z); }
        f32x4_t c1A = {0,0,0,0}, c1B = {0,0,0,0};

        #pragma unroll 1
        for (int c = 0; c <= TT/CHUNK; ++c) {
            if (c > 0) {
                const int cc   = c - 1;
                const int sb   = cc*CHUNK;
                const int half = (cc & 1)*CHUNK;
                #pragma unroll
                for (int j = 0; j < CHUNK; ++j) {
                    const int s = sb + j;
                    bf16x8_t A1 = *(const bf16x8_t*)&ring[half + j][n][q*8];
                    f32x4_t dI0 = MF(wi1[0][0], A1, bq1[0][0]);
                    f32x4_t dF0 = MF(wi1[1][0], A1, bq1[1][0]);
                    f32x4_t dG0 = MF(wi1[2][0], A1, bq1[2][0]);
                    f32x4_t dO0 = MF(wi1[3][0], A1, bq1[3][0]);
                    f32x4_t dI1 = MF(wi1[0][1], A1, bq1[0][1]);
                    f32x4_t dF1 = MF(wi1[1][1], A1, bq1[1][1]);
                    f32x4_t dG1 = MF(wi1[2][1], A1, bq1[2][1]);
                    f32x4_t dO1 = MF(wi1[3][1], A1, bq1[3][1]);
                    dI0 = MF(wh1[0][0], h1frag, dI0);
                    dF0 = MF(wh1[1][0], h1frag, dF0);
                    dG0 = MF(wh1[2][0], h1frag, dG0);
                    dO0 = MF(wh1[3][0], h1frag, dO0);
                    dI1 = MF(wh1[0][1], h1frag, dI1);
                    dF1 = MF(wh1[1][1], h1frag, dF1);
                    dG1 = MF(wh1[2][1], h1frag, dG1);
                    dO1 = MF(wh1[3][1], h1frag, dO1);
                    f32x4_t h1A = lstm_act(dI0, dF0, dG0, dO0, c1A);
                    f32x4_t h1B = lstm_act(dI1, dF1, dG1, dO1, c1B);
                    if (s == TT-1) {
                        *(f32x4_t*)&h1_last[n][q4]    = h1A;
                        *(f32x4_t*)&h1_last[n][16+q4] = h1B;
                    } else {
                        XPOSE(h1A, h1B, 0u, h1frag);
                    }
                }
            }
            __syncthreads();
        }
    }
#undef XPOSE
#undef BP
#undef MF

    // ---- FC head (128 threads, 16 rows) ----
    #pragma unroll
    for (int rep = 0; rep < 8; ++rep) {
        int idx = tid + rep*128;          // 16*64 outputs
        int m = idx >> 6, uu = idx & 63;
        float a = bfc1[uu];
        for (int k = 0; k < HID; ++k) a += h1_last[m][k] * Wfc1[uu*HID+k];
        zbuf[m][uu] = fmaxf(a, 0.f);
    }
    __syncthreads();
    #pragma unroll
    for (int rep = 0; rep < 4; ++rep) {
        int idx = tid + rep*128;          // 16*32 outputs
        int m = idx >> 5, v = idx & 31;
        float a = bfc2[v];
        for (int k = 0; k < 64; ++k) a += zbuf[m][k] * Wfc2[v*64+k];
        z2buf[m][v] = fmaxf(a, 0.f);
    }
    __syncthreads();
    if (tid < 16) {
        float a = bfc3[0];
        for (int k = 0; k < 32; ++k) a += z2buf[tid][k] * Wfc3[k];
        out[bbase + tid] = fsigmoid(a);
    }
}

extern "C" void kernel_launch(void* const* d_in, const int* in_sizes, int n_in,
                              void* d_out, int out_size, void* d_ws, size_t ws_size,
                              hipStream_t stream) {
    const float* x    = (const float*)d_in[0];
    const float* Wih0 = (const float*)d_in[1];
    const float* Whh0 = (const float*)d_in[2];
    const float* bih0 = (const float*)d_in[3];
    const float* bhh0 = (const float*)d_in[4];
    const float* Wih1 = (const float*)d_in[5];
    const float* Whh1 = (const float*)d_in[6];
    const float* bih1 = (const float*)d_in[7];
    const float* bhh1 = (const float*)d_in[8];
    const float* Wfc1 = (const float*)d_in[9];
    const float* bfc1 = (const float*)d_in[10];
    const float* Wfc2 = (const float*)d_in[11];
    const float* bfc2 = (const float*)d_in[12];
    const float* Wfc3 = (const float*)d_in[13];
    const float* bfc3 = (const float*)d_in[14];
    float* outp = (float*)d_out;

    hipLaunchKernelGGL(lstm_fused, dim3(512), dim3(128), 0, stream,
        x, Wih0, Whh0, bih0, bhh0, Wih1, Whh1, bih1, bhh1,
        Wfc1, bfc1, Wfc2, bfc2, Wfc3, bfc3, outp);
}

// Round 10
// 277.870 us; speedup vs baseline: 1.4621x; 1.0279x over previous
//
#include <hip/hip_runtime.h>

#define TT    256
#define HID   30
#define LOG2E 1.4426950408889634f
#define HS    40   // ring row stride (bf16)
#define NR    16   // ring slots = 2 chunks (double buffer)
#define CHUNK 8

typedef __bf16 bf16x8_t __attribute__((ext_vector_type(8)));
typedef float  f32x4_t  __attribute__((ext_vector_type(4)));
typedef unsigned int u32x4_t __attribute__((ext_vector_type(4)));

__device__ __forceinline__ float fexp2(float x){
#if __has_builtin(__builtin_amdgcn_exp2f)
    return __builtin_amdgcn_exp2f(x);
#else
    return exp2f(x);
#endif
}
__device__ __forceinline__ float frcp(float x){
#if __has_builtin(__builtin_amdgcn_rcpf)
    return __builtin_amdgcn_rcpf(x);
#else
    return 1.f/x;
#endif
}
__device__ __forceinline__ float fsigmoid(float x){ return frcp(1.f + fexp2(-LOG2E*x)); }
__device__ __forceinline__ f32x4_t exp4(f32x4_t v){
    f32x4_t e; e[0]=fexp2(v[0]); e[1]=fexp2(v[1]); e[2]=fexp2(v[2]); e[3]=fexp2(v[3]); return e;
}
__device__ __forceinline__ f32x4_t rcp4(f32x4_t v){
    f32x4_t r; r[0]=frcp(v[0]); r[1]=frcp(v[1]); r[2]=frcp(v[2]); r[3]=frcp(v[3]); return r;
}

__device__ __forceinline__ uint32_t pk_bf16(float lo, float hi){
    uint32_t r;
    asm("v_cvt_pk_bf16_f32 %0, %1, %2" : "=v"(r) : "v"(lo), "v"(hi));
    return r;
}

// Accs arrive pre-scaled into exp2 domain (scale folded into weights/biases):
//   aI,aF,aO = -LOG2E*z ; aG = +2*LOG2E*z
// Merged-rcp activation: 28 trans insts (20 exp + 8 rcp) per 4-vec.
__device__ __forceinline__ f32x4_t lstm_act(f32x4_t aI, f32x4_t aF, f32x4_t aG,
                                            f32x4_t aO, f32x4_t& cst){
    f32x4_t eI = exp4(aI);
    f32x4_t eF = exp4(aF);
    f32x4_t eG = exp4(aG);
    f32x4_t eO = exp4(aO);
    f32x4_t D1 = eF + 1.f;
    f32x4_t tG = eG + 1.f;
    f32x4_t D2 = eI*tG + tG;           // (1+eI)(1+eG)
    f32x4_t r  = rcp4(D1*D2);
    f32x4_t f  = r*D2;                 // sigmoid(zf)
    f32x4_t p  = (eG - 1.f) * (r*D1);  // i*tanh(zg)
    cst = f*cst + p;
    f32x4_t cc;                        // clamp so e^{2c} can't overflow
    cc[0]=fminf(fmaxf(cst[0],-30.f),30.f);
    cc[1]=fminf(fmaxf(cst[1],-30.f),30.f);
    cc[2]=fminf(fmaxf(cst[2],-30.f),30.f);
    cc[3]=fminf(fmaxf(cst[3],-30.f),30.f);
    f32x4_t eC = exp4(cc * (2.f*LOG2E));
    f32x4_t tC = eC + 1.f;
    f32x4_t dn = eO*tC + tC;           // (1+eO)(1+eC)
    return (eC - 1.f) * rcp4(dn);
}

// R9 (resubmit; previous run died on container infra, not the kernel):
// R8's chunked producer/consumer pipeline, re-shaped for wave placement.
// 256-thread block (4 waves) = TWO independent 16-row pipes:
//   wv0 = L0(pipeA), wv1 = L1(pipeA), wv2 = L0(pipeB), wv3 = L1(pipeB)
// Grid 256 -> 1 block/CU; round-robin wave placement puts one wave on each
// of the 4 SIMDs (R7/R8's 2-wave blocks could pack producer+consumer onto
// the same SIMD pair - the suspected 2x serialization, VALUBusy ~53% = half
// the SIMDs idle). Register-resident recurrences (XPOSE: cvt_pk +
// ds_bpermute, R6-validated); 16-slot ring per pipe, ONE barrier per
// 8-step chunk. x is prefetched into registers one chunk ahead (global
// loads drain only at the chunk barrier, ~8cy/step amortized).
__global__ __launch_bounds__(256, 1)
void lstm_fused(const float* __restrict__ x,
    const float* __restrict__ Wih0, const float* __restrict__ Whh0,
    const float* __restrict__ bih0, const float* __restrict__ bhh0,
    const float* __restrict__ Wih1, const float* __restrict__ Whh1,
    const float* __restrict__ bih1, const float* __restrict__ bhh1,
    const float* __restrict__ Wfc1, const float* __restrict__ bfc1,
    const float* __restrict__ Wfc2, const float* __restrict__ bfc2,
    const float* __restrict__ Wfc3, const float* __restrict__ bfc3,
    float* __restrict__ out)
{
    __shared__ __align__(16) __bf16 ring[2][NR][16][HS];  // 41KB (2 pipes)
    __shared__ float h1_last[32][32];
    __shared__ float zbuf[32][64];
    __shared__ float z2buf[32][32];

    const int tid  = threadIdx.x;
    const int lane = tid & 63;
    const int wv   = tid >> 6;     // 0..3
    const int pipe = wv >> 1;      // 0,1 : independent 16-row pipes
    const int role = wv & 1;       // 0 = L0 producer, 1 = L1 consumer
    const int n    = lane & 15;
    const int q    = lane >> 4;
    const int q4   = q*4;
    const int brow  = blockIdx.x * 32;
    const int bbase = brow + pipe*16;

    // transpose constants (R6/R7/R8-validated mapping)
    const int  ad01 = 4*(n + 32*(q & 1));
    const int  ad23 = ad01 + 64;
    const bool qlo  = (q < 2);
    const bool q3   = (q == 3);

#define MF(A,B,C) __builtin_amdgcn_mfma_f32_16x16x32_bf16((A),(B),(C),0,0,0)
#define BP(a,s)   ((uint32_t)__builtin_amdgcn_ds_bpermute((a),(int)(s)))
#define XPOSE(hA, hB, XW, dst) do {                                            \
    uint32_t a01=pk_bf16((hA)[0],(hA)[1]), a23=pk_bf16((hA)[2],(hA)[3]);       \
    uint32_t b01=pk_bf16((hB)[0],(hB)[1]), b23=pk_bf16((hB)[2],(hB)[3]);       \
    uint32_t t0a=BP(ad01,a01), t1a=BP(ad01,a23), t2a=BP(ad23,a01), t3a=BP(ad23,a23); \
    uint32_t t0b=BP(ad01,b01), t1b=BP(ad01,b23), t2b=BP(ad23,b01), t3b=BP(ad23,b23); \
    u32x4_t fw;                                                                \
    fw[0] = qlo ? t0a : t0b;                                                   \
    fw[1] = qlo ? t1a : t1b;                                                   \
    fw[2] = qlo ? t2a : t2b;                                                   \
    fw[3] = q3 ? (XW) : (qlo ? t3a : t3b);                                     \
    (dst) = __builtin_bit_cast(bf16x8_t, fw);                                  \
} while (0)

    const float scl[4] = {-LOG2E, -LOG2E, 2.f*LOG2E, -LOG2E}; // i,f,g,o

    if (role == 0) {
        // =========================== LAYER-0 wave ===========================
        bf16x8_t w0[4][2];
        f32x4_t  bq0[4][2], wxq[4][2];
        #pragma unroll
        for (int g = 0; g < 4; ++g) {
            #pragma unroll
            for (int ch = 0; ch < 2; ++ch) {
                const float sg = scl[g];
                const int uf = ch*16 + n;
                const int uqf = (uf < HID) ? uf : 0;
                const int rowf = g*HID + uqf;
                bf16x8_t a{};
                #pragma unroll
                for (int j = 0; j < 8; ++j) {
                    const int k = q*8 + j;
                    float va;
                    if (k < HID)       va = Whh0[rowf*HID + k];
                    else if (k == 30)  va = Wih0[rowf*3 + 0];
                    else               va = Wih0[rowf*3 + 1];
                    a[j] = (__bf16)(sg*va);
                }
                w0[g][ch] = a;
                f32x4_t b0v, wxv;
                #pragma unroll
                for (int r = 0; r < 4; ++r) {
                    const int ub = ch*16 + q4 + r;
                    const int uqb = (ub < HID) ? ub : 0;
                    const int rowb = g*HID + uqb;
                    b0v[r] = sg*(bih0[rowb] + bhh0[rowb]);
                    wxv[r] = sg*Wih0[rowb*3 + 2];
                }
                bq0[g][ch] = b0v;  wxq[g][ch] = wxv;
            }
        }

        // x prefetch: lane n streams row (bbase+n); current + next chunk in regs
        const float* xr = x + (size_t)(bbase + n) * (TT*3);
        float cx0[CHUNK], cx1[CHUNK], cx2[CHUNK];
        float nx0[CHUNK], nx1[CHUNK], nx2[CHUNK];
        #pragma unroll
        for (int j = 0; j < CHUNK; ++j) {
            cx0[j]=xr[3*j]; cx1[j]=xr[3*j+1]; cx2[j]=xr[3*j+2];
        }

        bf16x8_t h0frag;
        {
            u32x4_t z = {0u,0u,0u,0u};
            if (q3) z[3] = pk_bf16(cx0[0], cx1[0]);   // x01(t=0)
            h0frag = __builtin_bit_cast(bf16x8_t, z);
        }
        f32x4_t c0A = {0,0,0,0}, c0B = {0,0,0,0};

        #pragma unroll 1
        for (int c = 0; c <= TT/CHUNK; ++c) {
            if (c < TT/CHUNK) {
                {   // issue next-chunk x loads (drained by the chunk barrier)
                    const int nb = (c+1)*CHUNK;
                    #pragma unroll
                    for (int j = 0; j < CHUNK; ++j) {
                        int tp = nb + j;  if (tp > TT-1) tp = TT-1;
                        nx0[j]=xr[3*tp]; nx1[j]=xr[3*tp+1]; nx2[j]=xr[3*tp+2];
                    }
                }
                const int half = (c & 1)*CHUNK;
                #pragma unroll
                for (int j = 0; j < CHUNK; ++j) {
                    const float x2v = cx2[j];
                    f32x4_t aI0 = MF(w0[0][0], h0frag, bq0[0][0] + wxq[0][0]*x2v);
                    f32x4_t aF0 = MF(w0[1][0], h0frag, bq0[1][0] + wxq[1][0]*x2v);
                    f32x4_t aG0 = MF(w0[2][0], h0frag, bq0[2][0] + wxq[2][0]*x2v);
                    f32x4_t aO0 = MF(w0[3][0], h0frag, bq0[3][0] + wxq[3][0]*x2v);
                    f32x4_t aI1 = MF(w0[0][1], h0frag, bq0[0][1] + wxq[0][1]*x2v);
                    f32x4_t aF1 = MF(w0[1][1], h0frag, bq0[1][1] + wxq[1][1]*x2v);
                    f32x4_t aG1 = MF(w0[2][1], h0frag, bq0[2][1] + wxq[2][1]*x2v);
                    f32x4_t aO1 = MF(w0[3][1], h0frag, bq0[3][1] + wxq[3][1]*x2v);
                    f32x4_t h0A = lstm_act(aI0, aF0, aG0, aO0, c0A);
                    f32x4_t h0B = lstm_act(aI1, aF1, aG1, aO1, c0B);
                    const uint32_t XW = (j < CHUNK-1) ? pk_bf16(cx0[j+1], cx1[j+1])
                                                      : pk_bf16(nx0[0],  nx1[0]);
                    XPOSE(h0A, h0B, XW, h0frag);
                    *(bf16x8_t*)&ring[pipe][half + j][n][q*8] = h0frag;  // publish
                }
                #pragma unroll
                for (int j = 0; j < CHUNK; ++j) {
                    cx0[j]=nx0[j]; cx1[j]=nx1[j]; cx2[j]=nx2[j];
                }
            }
            __syncthreads();
        }
    } else {
        // =========================== LAYER-1 wave ===========================
        bf16x8_t wi1[4][2], wh1[4][2];
        f32x4_t  bq1[4][2];
        #pragma unroll
        for (int g = 0; g < 4; ++g) {
            #pragma unroll
            for (int ch = 0; ch < 2; ++ch) {
                const float sg = scl[g];
                const int uf = ch*16 + n;
                const int uqf = (uf < HID) ? uf : 0;
                const int rowf = g*HID + uqf;
                bf16x8_t a{}, b{};
                #pragma unroll
                for (int j = 0; j < 8; ++j) {
                    const int k = q*8 + j;
                    float va = 0.f, vb = 0.f;
                    if (k < HID) { va = Wih1[rowf*HID + k];  vb = Whh1[rowf*HID + k]; }
                    a[j] = (__bf16)(sg*va);
                    b[j] = (__bf16)(sg*vb);
                }
                wi1[g][ch] = a;  wh1[g][ch] = b;
                f32x4_t b1v;
                #pragma unroll
                for (int r = 0; r < 4; ++r) {
                    const int ub = ch*16 + q4 + r;
                    const int uqb = (ub < HID) ? ub : 0;
                    const int rowb = g*HID + uqb;
                    b1v[r] = sg*(bih1[rowb] + bhh1[rowb]);
                }
                bq1[g][ch] = b1v;
            }
        }

        bf16x8_t h1frag;
        { u32x4_t z = {0u,0u,0u,0u}; h1frag = __builtin_bit_cast(bf16x8_t, z); }
        f32x4_t c1A = {0,0,0,0}, c1B = {0,0,0,0};

        #pragma unroll 1
        for (int c = 0; c <= TT/CHUNK; ++c) {
            if (c > 0) {
                const int cc   = c - 1;
                const int sb   = cc*CHUNK;
                const int half = (cc & 1)*CHUNK;
                #pragma unroll
                for (int j = 0; j < CHUNK; ++j) {
                    const int s = sb + j;
                    bf16x8_t A1 = *(const bf16x8_t*)&ring[pipe][half + j][n][q*8];
                    f32x4_t dI0 = MF(wi1[0][0], A1, bq1[0][0]);
                    f32x4_t dF0 = MF(wi1[1][0], A1, bq1[1][0]);
                    f32x4_t dG0 = MF(wi1[2][0], A1, bq1[2][0]);
                    f32x4_t dO0 = MF(wi1[3][0], A1, bq1[3][0]);
                    f32x4_t dI1 = MF(wi1[0][1], A1, bq1[0][1]);
                    f32x4_t dF1 = MF(wi1[1][1], A1, bq1[1][1]);
                    f32x4_t dG1 = MF(wi1[2][1], A1, bq1[2][1]);
                    f32x4_t dO1 = MF(wi1[3][1], A1, bq1[3][1]);
                    dI0 = MF(wh1[0][0], h1frag, dI0);
                    dF0 = MF(wh1[1][0], h1frag, dF0);
                    dG0 = MF(wh1[2][0], h1frag, dG0);
                    dO0 = MF(wh1[3][0], h1frag, dO0);
                    dI1 = MF(wh1[0][1], h1frag, dI1);
                    dF1 = MF(wh1[1][1], h1frag, dF1);
                    dG1 = MF(wh1[2][1], h1frag, dG1);
                    dO1 = MF(wh1[3][1], h1frag, dO1);
                    f32x4_t h1A = lstm_act(dI0, dF0, dG0, dO0, c1A);
                    f32x4_t h1B = lstm_act(dI1, dF1, dG1, dO1, c1B);
                    if (s == TT-1) {
                        *(f32x4_t*)&h1_last[pipe*16 + n][q4]    = h1A;
                        *(f32x4_t*)&h1_last[pipe*16 + n][16+q4] = h1B;
                    } else {
                        XPOSE(h1A, h1B, 0u, h1frag);
                    }
                }
            }
            __syncthreads();
        }
    }
#undef XPOSE
#undef BP
#undef MF

    // ---- FC head (256 threads, 32 rows) ----
    #pragma unroll
    for (int rep = 0; rep < 8; ++rep) {
        int idx = tid + rep*256;          // 32*64 outputs
        int m = idx >> 6, uu = idx & 63;
        float a = bfc1[uu];
        for (int k = 0; k < HID; ++k) a += h1_last[m][k] * Wfc1[uu*HID+k];
        zbuf[m][uu] = fmaxf(a, 0.f);
    }
    __syncthreads();
    #pragma unroll
    for (int rep = 0; rep < 4; ++rep) {
        int idx = tid + rep*256;          // 32*32 outputs
        int m = idx >> 5, v = idx & 31;
        float a = bfc2[v];
        for (int k = 0; k < 64; ++k) a += zbuf[m][k] * Wfc2[v*64+k];
        z2buf[m][v] = fmaxf(a, 0.f);
    }
    __syncthreads();
    if (tid < 32) {
        float a = bfc3[0];
        for (int k = 0; k < 32; ++k) a += z2buf[tid][k] * Wfc3[k];
        out[brow + tid] = fsigmoid(a);
    }
}

extern "C" void kernel_launch(void* const* d_in, const int* in_sizes, int n_in,
                              void* d_out, int out_size, void* d_ws, size_t ws_size,
                              hipStream_t stream) {
    const float* x    = (const float*)d_in[0];
    const float* Wih0 = (const float*)d_in[1];
    const float* Whh0 = (const float*)d_in[2];
    const float* bih0 = (const float*)d_in[3];
    const float* bhh0 = (const float*)d_in[4];
    const float* Wih1 = (const float*)d_in[5];
    const float* Whh1 = (const float*)d_in[6];
    const float* bih1 = (const float*)d_in[7];
    const float* bhh1 = (const float*)d_in[8];
    const float* Wfc1 = (const float*)d_in[9];
    const float* bfc1 = (const float*)d_in[10];
    const float* Wfc2 = (const float*)d_in[11];
    const float* bfc2 = (const float*)d_in[12];
    const float* Wfc3 = (const float*)d_in[13];
    const float* bfc3 = (const float*)d_in[14];
    float* outp = (float*)d_out;

    hipLaunchKernelGGL(lstm_fused, dim3(256), dim3(256), 0, stream,
        x, Wih0, Whh0, bih0, bhh0, Wih1, Whh1, bih1, bhh1,
        Wfc1, bfc1, Wfc2, bfc2, Wfc3, bfc3, outp);
}